// Round 1
// baseline (18640.250 us; speedup 1.0000x reference)
//
#include <hip/hip_runtime.h>
#include <hip/hip_bf16.h>
#include <math.h>

#define NNODES 50000
#define NEDGES 1600000
#define NODEF 92
#define EDGEF 41
#define HID 128
#define NCONV 3
#define NGRAPHS 256
#define ZDIM 297            // 2*HID + EDGEF
#define ZPAD 304            // pad K to multiple of 16 (float4-friendly)
#define TE 16               // edges per block

__device__ __forceinline__ float softplus_f(float x) {
    // matches jax.nn.softplus = max(x,0) + log1p(exp(-|x|))
    return fmaxf(x, 0.f) + log1pf(expf(-fabsf(x)));
}
__device__ __forceinline__ float sigmoid_f(float x) {
    return 1.f / (1.f + expf(-x));
}

// WT[l][j][k]: j<128 -> msg_w (sigmoid branch) col j ; j>=128 -> gate_w (softplus) col j-128
// k zero-padded ZDIM..ZPAD
__global__ void prep_wt(const float* __restrict__ msg_w, const float* __restrict__ gate_w,
                        float* __restrict__ wt) {
    int idx = blockIdx.x * blockDim.x + threadIdx.x;
    const int total = NCONV * 256 * ZPAD;
    for (; idx < total; idx += gridDim.x * blockDim.x) {
        int k = idx % ZPAD;
        int j = (idx / ZPAD) % 256;
        int l = idx / (ZPAD * 256);
        float v = 0.f;
        if (k < ZDIM) {
            if (j < HID) v = msg_w[((size_t)l * ZDIM + k) * HID + j];
            else         v = gate_w[((size_t)l * ZDIM + k) * HID + (j - HID)];
        }
        wt[idx] = v;
    }
}

__global__ void embed_kernel(const float* __restrict__ x, const float* __restrict__ w,
                             const float* __restrict__ b, float* __restrict__ h) {
    __shared__ float xs[NODEF];
    const int n = blockIdx.x;
    const int j = threadIdx.x;
    if (j < NODEF) xs[j] = x[(size_t)n * NODEF + j];
    __syncthreads();
    float acc = b[j];
    #pragma unroll 4
    for (int k = 0; k < NODEF; ++k) acc = fmaf(xs[k], w[k * HID + j], acc);
    h[(size_t)n * HID + j] = acc;
}

__global__ __launch_bounds__(256) void edge_kernel(
    const float* __restrict__ h, const int* __restrict__ ei,
    const float* __restrict__ ea, const float* __restrict__ wt,
    const float* __restrict__ bm, const float* __restrict__ bg,
    float* __restrict__ aggr) {
    __shared__ __align__(16) float zs[TE][ZPAD];   // 19456 B
    __shared__ float ms[TE][HID];                  // sigmoid values, 8 KB
    __shared__ int sidx[2 * TE];

    const int t = threadIdx.x;
    const int eb = blockIdx.x * TE;

    if (t < TE) sidx[t] = ei[eb + t];                              // dst
    else if (t < 2 * TE) sidx[t] = ei[NEDGES + eb + (t - TE)];     // src
    __syncthreads();

    {   // cooperative gather of z rows: 16 threads per edge row
        const int r = t >> 4, c0 = t & 15;
        const float* hd = h + (size_t)sidx[r] * HID;
        const float* hs = h + (size_t)sidx[TE + r] * HID;
        const float* er = ea + (size_t)(eb + r) * EDGEF;
        for (int k = c0; k < ZPAD; k += 16) {
            float v;
            if (k < HID)          v = hd[k];
            else if (k < 2 * HID) v = hs[k - HID];
            else if (k < ZDIM)    v = er[k - 2 * HID];
            else                  v = 0.f;
            zs[r][k] = v;
        }
    }
    __syncthreads();

    float acc[TE];
    #pragma unroll
    for (int e = 0; e < TE; ++e) acc[e] = 0.f;

    const float4* wrow = (const float4*)(wt + (size_t)t * ZPAD);
    #pragma unroll 2
    for (int k4 = 0; k4 < ZPAD / 4; ++k4) {
        const float4 w = wrow[k4];
        #pragma unroll
        for (int e = 0; e < TE; ++e) {
            const float4 z = *(const float4*)(&zs[e][k4 * 4]);
            float a = acc[e];
            a = fmaf(z.x, w.x, a);
            a = fmaf(z.y, w.y, a);
            a = fmaf(z.z, w.z, a);
            a = fmaf(z.w, w.w, a);
            acc[e] = a;
        }
    }

    if (t < HID) {
        const float b = bm[t];
        #pragma unroll
        for (int e = 0; e < TE; ++e) ms[e][t] = sigmoid_f(acc[e] + b);
    }
    __syncthreads();
    if (t >= HID) {
        const int j = t - HID;
        const float b = bg[j];
        #pragma unroll
        for (int e = 0; e < TE; ++e) {
            const float p = softplus_f(acc[e] + b);
            atomicAdd(&aggr[(size_t)sidx[e] * HID + j], ms[e][j] * p);
        }
    }
}

__global__ void update_kernel(float* __restrict__ h, const float* __restrict__ aggr) {
    const size_t idx = (size_t)blockIdx.x * blockDim.x + threadIdx.x;
    float4 hv = ((const float4*)h)[idx];
    const float4 av = ((const float4*)aggr)[idx];
    hv.x = softplus_f(hv.x + av.x);
    hv.y = softplus_f(hv.y + av.y);
    hv.z = softplus_f(hv.z + av.z);
    hv.w = softplus_f(hv.w + av.w);
    ((float4*)h)[idx] = hv;
}

__global__ void readout_kernel(const float* __restrict__ h, const int* __restrict__ batch,
                               const float* __restrict__ ro1w, const float* __restrict__ ro1b,
                               const float* __restrict__ ro2w, const float* __restrict__ ro2b,
                               float* __restrict__ out) {
    __shared__ float pooled[HID];
    __shared__ float red[HID];
    __shared__ int range[2];
    const int g = blockIdx.x, j = threadIdx.x;
    if (j == 0) {
        int lo = 0, hi = NNODES;
        while (lo < hi) { int mid = (lo + hi) >> 1; if (batch[mid] < g) lo = mid + 1; else hi = mid; }
        range[0] = lo;
        hi = NNODES;
        while (lo < hi) { int mid = (lo + hi) >> 1; if (batch[mid] < g + 1) lo = mid + 1; else hi = mid; }
        range[1] = lo;
    }
    __syncthreads();
    const int start = range[0], end = range[1];
    float s = 0.f;
    for (int n = start; n < end; ++n) s += h[(size_t)n * HID + j];
    const float cnt = (float)(end - start);
    pooled[j] = s / fmaxf(cnt, 1.f);
    __syncthreads();
    float acc = ro1b[j];
    #pragma unroll 4
    for (int k = 0; k < HID; ++k) acc = fmaf(pooled[k], ro1w[k * HID + j], acc);
    red[j] = softplus_f(acc) * ro2w[j];
    __syncthreads();
    for (int sdt = 64; sdt > 0; sdt >>= 1) {
        if (j < sdt) red[j] += red[j + sdt];
        __syncthreads();
    }
    if (j == 0) out[g] = red[0] + ro2b[0];
}

extern "C" void kernel_launch(void* const* d_in, const int* in_sizes, int n_in,
                              void* d_out, int out_size, void* d_ws, size_t ws_size,
                              hipStream_t stream) {
    (void)in_sizes; (void)n_in; (void)out_size; (void)ws_size;
    const float* x      = (const float*)d_in[0];
    const int*   ei     = (const int*)d_in[1];
    const float* ea     = (const float*)d_in[2];
    const int*   batch  = (const int*)d_in[3];
    const float* emb_w  = (const float*)d_in[4];
    const float* emb_b  = (const float*)d_in[5];
    const float* msg_w  = (const float*)d_in[6];
    const float* msg_b  = (const float*)d_in[7];
    const float* gate_w = (const float*)d_in[8];
    const float* gate_b = (const float*)d_in[9];
    const float* ro1w   = (const float*)d_in[10];
    const float* ro1b   = (const float*)d_in[11];
    const float* ro2w   = (const float*)d_in[12];
    const float* ro2b   = (const float*)d_in[13];
    float* out = (float*)d_out;

    float* ws   = (float*)d_ws;
    float* h    = ws;                                  // NNODES*HID
    float* aggr = h + (size_t)NNODES * HID;            // NNODES*HID
    float* wt   = aggr + (size_t)NNODES * HID;         // NCONV*256*ZPAD

    prep_wt<<<256, 256, 0, stream>>>(msg_w, gate_w, wt);
    embed_kernel<<<NNODES, HID, 0, stream>>>(x, emb_w, emb_b, h);

    for (int l = 0; l < NCONV; ++l) {
        hipMemsetAsync(aggr, 0, (size_t)NNODES * HID * sizeof(float), stream);
        edge_kernel<<<NEDGES / TE, 256, 0, stream>>>(
            h, ei, ea, wt + (size_t)l * 256 * ZPAD,
            msg_b + l * HID, gate_b + l * HID, aggr);
        update_kernel<<<(NNODES * HID / 4) / 256, 256, 0, stream>>>(h, aggr);
    }

    readout_kernel<<<NGRAPHS, HID, 0, stream>>>(h, batch, ro1w, ro1b, ro2w, ro2b, out);
}

// Round 2
// 4534.667 us; speedup vs baseline: 4.1106x; 4.1106x over previous
//
#include <hip/hip_runtime.h>
#include <hip/hip_bf16.h>
#include <math.h>

#define NNODES 50000
#define NEDGES 1600000
#define NODEF 92
#define EDGEF 41
#define HID 128
#define NCONV 3
#define NGRAPHS 256
#define ZDIM 297            // 2*HID + EDGEF
#define KPAD 320            // pad K to 10 MFMA steps of 32
#define KSTEPS 10
#define ZLD 328             // LDS leading dim in f16: 164 words % 32 = 4 -> 2-way banks
#define ME 32               // edges per block

typedef _Float16 half8 __attribute__((ext_vector_type(8)));
typedef _Float16 half4 __attribute__((ext_vector_type(4)));
typedef float f32x4 __attribute__((ext_vector_type(4)));

__device__ __forceinline__ float softplus_f(float x) {
    return fmaxf(x, 0.f) + log1pf(expf(-fabsf(x)));
}
__device__ __forceinline__ float sigmoid_f(float x) {
    return 1.f / (1.f + expf(-x));
}

// B-fragment order: wf[((l*16 + g)*KSTEPS + ks)*64 + lane] = 8 contiguous f16.
// Tile g: branch = g&1 (0 = msg_w/sigmoid, 1 = gate_w/softplus),
//         j = (g>>2)*32 + ((g>>1)&1)*16 + (lane&15), k = ks*32 + (lane>>4)*8 + jj
__global__ void prep_wfrag(const float* __restrict__ msg_w, const float* __restrict__ gate_w,
                           half8* __restrict__ wf) {
    const int idx = blockIdx.x * blockDim.x + threadIdx.x;
    const int total = NCONV * 16 * KSTEPS * 64;
    if (idx >= total) return;
    const int lane = idx & 63;
    const int rest = idx >> 6;
    const int ks = rest % KSTEPS;
    const int gl = rest / KSTEPS;
    const int g = gl & 15;
    const int l = gl >> 4;
    const int branch = g & 1;
    const int j = (g >> 2) * 32 + ((g >> 1) & 1) * 16 + (lane & 15);
    const int k0 = ks * 32 + (lane >> 4) * 8;
    const float* W = branch ? gate_w : msg_w;
    half8 v;
    #pragma unroll
    for (int jj = 0; jj < 8; ++jj) {
        const int k = k0 + jj;
        const float f = (k < ZDIM) ? W[((size_t)l * ZDIM + k) * HID + j] : 0.f;
        v[jj] = (_Float16)f;
    }
    wf[idx] = v;
}

__global__ void embed_kernel(const float* __restrict__ x, const float* __restrict__ w,
                             const float* __restrict__ b, float* __restrict__ h) {
    __shared__ float xs[NODEF];
    const int n = blockIdx.x;
    const int j = threadIdx.x;
    if (j < NODEF) xs[j] = x[(size_t)n * NODEF + j];
    __syncthreads();
    float acc = b[j];
    #pragma unroll 4
    for (int k = 0; k < NODEF; ++k) acc = fmaf(xs[k], w[k * HID + j], acc);
    h[(size_t)n * HID + j] = acc;
}

__global__ __launch_bounds__(256) void edge_mfma_kernel(
    const float* __restrict__ h, const int* __restrict__ ei,
    const float* __restrict__ ea, const half8* __restrict__ wf,
    const float* __restrict__ bm, const float* __restrict__ bg,
    float* __restrict__ aggr) {
    __shared__ __align__(16) _Float16 zhi[ME][ZLD];
    __shared__ __align__(16) _Float16 zlo[ME][ZLD];
    __shared__ int sdst[ME];
    __shared__ int ssrc[ME];

    const int t = threadIdx.x;
    const int eb = blockIdx.x * ME;
    if (t < ME) sdst[t] = ei[eb + t];
    else if (t < 2 * ME) ssrc[t - ME] = ei[NEDGES + eb + (t - ME)];
    __syncthreads();

    // ---- stage z into LDS as fp16 hi/lo ----
    // h-part: k 0..255 = 64 float4 per row; per iter a wave covers one row
    // (lanes 0-31 dst-h, lanes 32-63 src-h) -> two coalesced 512B reads.
    #pragma unroll
    for (int i = 0; i < 8; ++i) {
        const int idx = t + 256 * i;
        const int r = idx >> 6;
        const int c4 = idx & 63;
        const float4 v = (c4 < 32)
            ? ((const float4*)(h + (size_t)sdst[r] * HID))[c4]
            : ((const float4*)(h + (size_t)ssrc[r] * HID))[c4 - 32];
        const _Float16 h0 = (_Float16)v.x, h1 = (_Float16)v.y,
                       h2 = (_Float16)v.z, h3 = (_Float16)v.w;
        *(half4*)&zhi[r][c4 * 4] = (half4){h0, h1, h2, h3};
        *(half4*)&zlo[r][c4 * 4] = (half4){(_Float16)(v.x - (float)h0),
                                           (_Float16)(v.y - (float)h1),
                                           (_Float16)(v.z - (float)h2),
                                           (_Float16)(v.w - (float)h3)};
    }
    // edge-attr + zero pad: k 256..319
    #pragma unroll
    for (int i = 0; i < 8; ++i) {
        const int idx = t + 256 * i;
        const int r = idx >> 6;
        const int k = 256 + (idx & 63);
        float f = 0.f;
        if (k < ZDIM) f = ea[(size_t)(eb + r) * EDGEF + (k - 256)];
        const _Float16 hi = (_Float16)f;
        zhi[r][k] = hi;
        zlo[r][k] = (_Float16)(f - (float)hi);
    }
    __syncthreads();

    // ---- MFMA: [32 x KPAD] @ [KPAD x 256] with z = zhi + zlo ----
    const int wave = t >> 6;
    const int lane = t & 63;
    const int arow = lane & 15;
    const int koff = (lane >> 4) * 8;

    f32x4 acc[2][4];
    #pragma unroll
    for (int m = 0; m < 2; ++m)
        #pragma unroll
        for (int n = 0; n < 4; ++n) acc[m][n] = (f32x4){0.f, 0.f, 0.f, 0.f};

    const half8* wfw = wf + (size_t)(wave * 4) * KSTEPS * 64 + lane;
    #pragma unroll 2
    for (int ks = 0; ks < KSTEPS; ++ks) {
        const int kb = ks * 32 + koff;
        const half8 a0h = *(const half8*)&zhi[arow][kb];
        const half8 a0l = *(const half8*)&zlo[arow][kb];
        const half8 a1h = *(const half8*)&zhi[16 + arow][kb];
        const half8 a1l = *(const half8*)&zlo[16 + arow][kb];
        #pragma unroll
        for (int nt = 0; nt < 4; ++nt) {
            const half8 b = wfw[(size_t)(nt * KSTEPS + ks) * 64];
            acc[0][nt] = __builtin_amdgcn_mfma_f32_16x16x32_f16(a0h, b, acc[0][nt], 0, 0, 0);
            acc[0][nt] = __builtin_amdgcn_mfma_f32_16x16x32_f16(a0l, b, acc[0][nt], 0, 0, 0);
            acc[1][nt] = __builtin_amdgcn_mfma_f32_16x16x32_f16(a1h, b, acc[1][nt], 0, 0, 0);
            acc[1][nt] = __builtin_amdgcn_mfma_f32_16x16x32_f16(a1l, b, acc[1][nt], 0, 0, 0);
        }
    }

    // ---- epilogue: gate*msg, atomic scatter-add ----
    // C layout: col = lane&15, row = (lane>>4)*4 + reg. Tiles 2p (msg,sigmoid)
    // and 2p+1 (gate,softplus) cover the same j-range -> lane-local pairing.
    #pragma unroll
    for (int p = 0; p < 2; ++p) {
        const int j = wave * 32 + p * 16 + (lane & 15);
        const float bmv = bm[j];
        const float bgv = bg[j];
        #pragma unroll
        for (int m = 0; m < 2; ++m) {
            #pragma unroll
            for (int r = 0; r < 4; ++r) {
                const int row = m * 16 + (lane >> 4) * 4 + r;
                const float gate = sigmoid_f(acc[m][2 * p][r] + bmv);
                const float msg = softplus_f(acc[m][2 * p + 1][r] + bgv);
                atomicAdd(&aggr[(size_t)sdst[row] * HID + j], gate * msg);
            }
        }
    }
}

__global__ void update_kernel(float* __restrict__ h, const float* __restrict__ aggr) {
    const size_t idx = (size_t)blockIdx.x * blockDim.x + threadIdx.x;
    float4 hv = ((const float4*)h)[idx];
    const float4 av = ((const float4*)aggr)[idx];
    hv.x = softplus_f(hv.x + av.x);
    hv.y = softplus_f(hv.y + av.y);
    hv.z = softplus_f(hv.z + av.z);
    hv.w = softplus_f(hv.w + av.w);
    ((float4*)h)[idx] = hv;
}

__global__ void readout_kernel(const float* __restrict__ h, const int* __restrict__ batch,
                               const float* __restrict__ ro1w, const float* __restrict__ ro1b,
                               const float* __restrict__ ro2w, const float* __restrict__ ro2b,
                               float* __restrict__ out) {
    __shared__ float pooled[HID];
    __shared__ float red[HID];
    __shared__ int range[2];
    const int g = blockIdx.x, j = threadIdx.x;
    if (j == 0) {
        int lo = 0, hi = NNODES;
        while (lo < hi) { int mid = (lo + hi) >> 1; if (batch[mid] < g) lo = mid + 1; else hi = mid; }
        range[0] = lo;
        hi = NNODES;
        while (lo < hi) { int mid = (lo + hi) >> 1; if (batch[mid] < g + 1) lo = mid + 1; else hi = mid; }
        range[1] = lo;
    }
    __syncthreads();
    const int start = range[0], end = range[1];
    float s = 0.f;
    for (int n = start; n < end; ++n) s += h[(size_t)n * HID + j];
    const float cnt = (float)(end - start);
    pooled[j] = s / fmaxf(cnt, 1.f);
    __syncthreads();
    float acc = ro1b[j];
    #pragma unroll 4
    for (int k = 0; k < HID; ++k) acc = fmaf(pooled[k], ro1w[k * HID + j], acc);
    red[j] = softplus_f(acc) * ro2w[j];
    __syncthreads();
    for (int sdt = 64; sdt > 0; sdt >>= 1) {
        if (j < sdt) red[j] += red[j + sdt];
        __syncthreads();
    }
    if (j == 0) out[g] = red[0] + ro2b[0];
}

extern "C" void kernel_launch(void* const* d_in, const int* in_sizes, int n_in,
                              void* d_out, int out_size, void* d_ws, size_t ws_size,
                              hipStream_t stream) {
    (void)in_sizes; (void)n_in; (void)out_size; (void)ws_size;
    const float* x      = (const float*)d_in[0];
    const int*   ei     = (const int*)d_in[1];
    const float* ea     = (const float*)d_in[2];
    const int*   batch  = (const int*)d_in[3];
    const float* emb_w  = (const float*)d_in[4];
    const float* emb_b  = (const float*)d_in[5];
    const float* msg_w  = (const float*)d_in[6];
    const float* msg_b  = (const float*)d_in[7];
    const float* gate_w = (const float*)d_in[8];
    const float* gate_b = (const float*)d_in[9];
    const float* ro1w   = (const float*)d_in[10];
    const float* ro1b   = (const float*)d_in[11];
    const float* ro2w   = (const float*)d_in[12];
    const float* ro2b   = (const float*)d_in[13];
    float* out = (float*)d_out;

    float* ws   = (float*)d_ws;
    float* h    = ws;                                  // NNODES*HID floats
    float* aggr = h + (size_t)NNODES * HID;            // NNODES*HID floats
    half8* wfrag = (half8*)(aggr + (size_t)NNODES * HID); // NCONV*16*KSTEPS*64 half8

    const int wtotal = NCONV * 16 * KSTEPS * 64;
    prep_wfrag<<<(wtotal + 255) / 256, 256, 0, stream>>>(msg_w, gate_w, wfrag);
    embed_kernel<<<NNODES, HID, 0, stream>>>(x, emb_w, emb_b, h);

    for (int l = 0; l < NCONV; ++l) {
        hipMemsetAsync(aggr, 0, (size_t)NNODES * HID * sizeof(float), stream);
        edge_mfma_kernel<<<NEDGES / ME, 256, 0, stream>>>(
            h, ei, ea, wfrag + (size_t)l * 16 * KSTEPS * 64,
            msg_b + l * HID, gate_b + l * HID, aggr);
        update_kernel<<<(NNODES * HID / 4) / 256, 256, 0, stream>>>(h, aggr);
    }

    readout_kernel<<<NGRAPHS, HID, 0, stream>>>(h, batch, ro1w, ro1b, ro2w, ro2b, out);
}

// Round 3
// 3029.786 us; speedup vs baseline: 6.1523x; 1.4967x over previous
//
#include <hip/hip_runtime.h>
#include <hip/hip_bf16.h>
#include <math.h>

#define NNODES 50000
#define NEDGES 1600000
#define NODEF 92
#define EDGEF 41
#define HID 128
#define NCONV 3
#define NGRAPHS 256
#define ZDIM 297            // 2*HID + EDGEF
#define KPAD 320            // pad K to 10 MFMA steps of 32
#define KSTEPS 10
#define ZLD 328             // LDS leading dim in f16: 164 words % 32 = 4 -> 2-way banks (free)
#define ME 32               // edges per block

typedef _Float16 half8 __attribute__((ext_vector_type(8)));
typedef _Float16 half4 __attribute__((ext_vector_type(4)));
typedef float f32x4 __attribute__((ext_vector_type(4)));

__device__ __forceinline__ float softplus_f(float x) {
    // fast: max(x,0) + log(1+exp(-|x|)) with native exp/log
    return fmaxf(x, 0.f) + __logf(1.f + __expf(-fabsf(x)));
}
__device__ __forceinline__ float sigmoid_f(float x) {
    return __builtin_amdgcn_rcpf(1.f + __expf(-x));
}

// B-fragment order: wf[((l*16 + g)*KSTEPS + ks)*64 + lane] = 8 contiguous f16.
// Tile g: branch = g&1 (0 = msg_w/sigmoid, 1 = gate_w/softplus),
//         j = (g>>2)*32 + ((g>>1)&1)*16 + (lane&15), k = ks*32 + (lane>>4)*8 + jj
__global__ void prep_wfrag(const float* __restrict__ msg_w, const float* __restrict__ gate_w,
                           half8* __restrict__ wf) {
    const int idx = blockIdx.x * blockDim.x + threadIdx.x;
    const int total = NCONV * 16 * KSTEPS * 64;
    if (idx >= total) return;
    const int lane = idx & 63;
    const int rest = idx >> 6;
    const int ks = rest % KSTEPS;
    const int gl = rest / KSTEPS;
    const int g = gl & 15;
    const int l = gl >> 4;
    const int branch = g & 1;
    const int j = (g >> 2) * 32 + ((g >> 1) & 1) * 16 + (lane & 15);
    const int k0 = ks * 32 + (lane >> 4) * 8;
    const float* W = branch ? gate_w : msg_w;
    half8 v;
    #pragma unroll
    for (int jj = 0; jj < 8; ++jj) {
        const int k = k0 + jj;
        const float f = (k < ZDIM) ? W[((size_t)l * ZDIM + k) * HID + j] : 0.f;
        v[jj] = (_Float16)f;
    }
    wf[idx] = v;
}

__global__ void embed_kernel(const float* __restrict__ x, const float* __restrict__ w,
                             const float* __restrict__ b, float* __restrict__ h) {
    __shared__ float xs[NODEF];
    const int n = blockIdx.x;
    const int j = threadIdx.x;
    if (j < NODEF) xs[j] = x[(size_t)n * NODEF + j];
    __syncthreads();
    float acc = b[j];
    #pragma unroll 4
    for (int k = 0; k < NODEF; ++k) acc = fmaf(xs[k], w[k * HID + j], acc);
    h[(size_t)n * HID + j] = acc;
}

__global__ __launch_bounds__(256) void edge_mfma_kernel(
    const float* __restrict__ h, const int* __restrict__ ei,
    const float* __restrict__ ea, const half8* __restrict__ wf,
    const float* __restrict__ bm, const float* __restrict__ bg,
    float* __restrict__ aggr) {
    __shared__ __align__(16) _Float16 zs[ME][ZLD];        // 21 KB
    __shared__ const float4* shp[2 * ME];                 // gather row pointers
    __shared__ float* sbase[ME];                          // aggr row bases

    const int t = threadIdx.x;
    const int eb = blockIdx.x * ME;
    if (t < ME) {
        const int d = ei[eb + t];
        shp[t] = (const float4*)(h + (size_t)d * HID);
        sbase[t] = aggr + (size_t)d * HID;
    } else if (t < 2 * ME) {
        shp[t] = (const float4*)(h + (size_t)ei[NEDGES + eb + (t - ME)] * HID);
    }
    __syncthreads();

    // ---- stage z into LDS as fp16 ----
    // h-part: k 0..255 -> 64 float4 per edge row; one wave covers one row/iter.
    #pragma unroll
    for (int i = 0; i < 8; ++i) {
        const int idx = t + 256 * i;
        const int r = idx >> 6;
        const int c4 = idx & 63;
        const float4 v = (c4 < 32) ? shp[r][c4] : shp[ME + r][c4 - 32];
        *(half4*)&zs[r][c4 * 4] = (half4){(_Float16)v.x, (_Float16)v.y,
                                          (_Float16)v.z, (_Float16)v.w};
    }
    // edge-attr + zero pad: k 256..319
    #pragma unroll
    for (int i = 0; i < 8; ++i) {
        const int idx = t + 256 * i;
        const int r = idx >> 6;
        const int k = 256 + (idx & 63);
        float f = 0.f;
        if (k < ZDIM) f = ea[(size_t)(eb + r) * EDGEF + (k - 256)];
        zs[r][k] = (_Float16)f;
    }
    __syncthreads();

    // ---- MFMA: [32 x KPAD] @ [KPAD x 256] ----
    const int wave = t >> 6;
    const int lane = t & 63;
    const int arow = lane & 15;
    const int koff = (lane >> 4) * 8;

    f32x4 acc[2][4];
    #pragma unroll
    for (int m = 0; m < 2; ++m)
        #pragma unroll
        for (int n = 0; n < 4; ++n) acc[m][n] = (f32x4){0.f, 0.f, 0.f, 0.f};

    const half8* wfw = wf + (size_t)(wave * 4) * KSTEPS * 64 + lane;
    #pragma unroll 2
    for (int ks = 0; ks < KSTEPS; ++ks) {
        const int kb = ks * 32 + koff;
        const half8 a0 = *(const half8*)&zs[arow][kb];
        const half8 a1 = *(const half8*)&zs[16 + arow][kb];
        #pragma unroll
        for (int nt = 0; nt < 4; ++nt) {
            const half8 b = wfw[(size_t)(nt * KSTEPS + ks) * 64];
            acc[0][nt] = __builtin_amdgcn_mfma_f32_16x16x32_f16(a0, b, acc[0][nt], 0, 0, 0);
            acc[1][nt] = __builtin_amdgcn_mfma_f32_16x16x32_f16(a1, b, acc[1][nt], 0, 0, 0);
        }
    }

    // ---- epilogue: gate*msg, atomic scatter-add ----
    // C layout: col = lane&15, row = (lane>>4)*4 + reg. Tiles 2p (msg,sigmoid)
    // and 2p+1 (gate,softplus) cover the same j-range -> lane-local pairing.
    const int j0 = wave * 32 + (lane & 15);
    const float bm0 = bm[j0], bm1 = bm[j0 + 16];
    const float bg0 = bg[j0], bg1 = bg[j0 + 16];
    #pragma unroll
    for (int m = 0; m < 2; ++m) {
        #pragma unroll
        for (int r = 0; r < 4; ++r) {
            const int row = m * 16 + (lane >> 4) * 4 + r;
            float* base = sbase[row];
            {
                const float gate = sigmoid_f(acc[m][0][r] + bm0);
                const float msg = softplus_f(acc[m][1][r] + bg0);
                atomicAdd(base + j0, gate * msg);
            }
            {
                const float gate = sigmoid_f(acc[m][2][r] + bm1);
                const float msg = softplus_f(acc[m][3][r] + bg1);
                atomicAdd(base + j0 + 16, gate * msg);
            }
        }
    }
}

__global__ void update_kernel(float* __restrict__ h, const float* __restrict__ aggr) {
    const size_t idx = (size_t)blockIdx.x * blockDim.x + threadIdx.x;
    float4 hv = ((const float4*)h)[idx];
    const float4 av = ((const float4*)aggr)[idx];
    hv.x = softplus_f(hv.x + av.x);
    hv.y = softplus_f(hv.y + av.y);
    hv.z = softplus_f(hv.z + av.z);
    hv.w = softplus_f(hv.w + av.w);
    ((float4*)h)[idx] = hv;
}

__global__ void readout_kernel(const float* __restrict__ h, const int* __restrict__ batch,
                               const float* __restrict__ ro1w, const float* __restrict__ ro1b,
                               const float* __restrict__ ro2w, const float* __restrict__ ro2b,
                               float* __restrict__ out) {
    __shared__ float pooled[HID];
    __shared__ float red[HID];
    __shared__ int range[2];
    const int g = blockIdx.x, j = threadIdx.x;
    if (j == 0) {
        int lo = 0, hi = NNODES;
        while (lo < hi) { int mid = (lo + hi) >> 1; if (batch[mid] < g) lo = mid + 1; else hi = mid; }
        range[0] = lo;
        hi = NNODES;
        while (lo < hi) { int mid = (lo + hi) >> 1; if (batch[mid] < g + 1) lo = mid + 1; else hi = mid; }
        range[1] = lo;
    }
    __syncthreads();
    const int start = range[0], end = range[1];
    float s = 0.f;
    for (int n = start; n < end; ++n) s += h[(size_t)n * HID + j];
    const float cnt = (float)(end - start);
    pooled[j] = s / fmaxf(cnt, 1.f);
    __syncthreads();
    float acc = ro1b[j];
    #pragma unroll 4
    for (int k = 0; k < HID; ++k) acc = fmaf(pooled[k], ro1w[k * HID + j], acc);
    red[j] = softplus_f(acc) * ro2w[j];
    __syncthreads();
    for (int sdt = 64; sdt > 0; sdt >>= 1) {
        if (j < sdt) red[j] += red[j + sdt];
        __syncthreads();
    }
    if (j == 0) out[g] = red[0] + ro2b[0];
}

extern "C" void kernel_launch(void* const* d_in, const int* in_sizes, int n_in,
                              void* d_out, int out_size, void* d_ws, size_t ws_size,
                              hipStream_t stream) {
    (void)in_sizes; (void)n_in; (void)out_size; (void)ws_size;
    const float* x      = (const float*)d_in[0];
    const int*   ei     = (const int*)d_in[1];
    const float* ea     = (const float*)d_in[2];
    const int*   batch  = (const int*)d_in[3];
    const float* emb_w  = (const float*)d_in[4];
    const float* emb_b  = (const float*)d_in[5];
    const float* msg_w  = (const float*)d_in[6];
    const float* msg_b  = (const float*)d_in[7];
    const float* gate_w = (const float*)d_in[8];
    const float* gate_b = (const float*)d_in[9];
    const float* ro1w   = (const float*)d_in[10];
    const float* ro1b   = (const float*)d_in[11];
    const float* ro2w   = (const float*)d_in[12];
    const float* ro2b   = (const float*)d_in[13];
    float* out = (float*)d_out;

    float* ws   = (float*)d_ws;
    float* h    = ws;                                  // NNODES*HID floats
    float* aggr = h + (size_t)NNODES * HID;            // NNODES*HID floats
    half8* wfrag = (half8*)(aggr + (size_t)NNODES * HID); // NCONV*16*KSTEPS*64 half8

    const int wtotal = NCONV * 16 * KSTEPS * 64;
    prep_wfrag<<<(wtotal + 255) / 256, 256, 0, stream>>>(msg_w, gate_w, wfrag);
    embed_kernel<<<NNODES, HID, 0, stream>>>(x, emb_w, emb_b, h);

    for (int l = 0; l < NCONV; ++l) {
        hipMemsetAsync(aggr, 0, (size_t)NNODES * HID * sizeof(float), stream);
        edge_mfma_kernel<<<NEDGES / ME, 256, 0, stream>>>(
            h, ei, ea, wfrag + (size_t)l * 16 * KSTEPS * 64,
            msg_b + l * HID, gate_b + l * HID, aggr);
        update_kernel<<<(NNODES * HID / 4) / 256, 256, 0, stream>>>(h, aggr);
    }

    readout_kernel<<<NGRAPHS, HID, 0, stream>>>(h, batch, ro1w, ro1b, ro2w, ro2b, out);
}